// Round 2
// baseline (1593.800 us; speedup 1.0000x reference)
//
#include <hip/hip_runtime.h>
#include <math.h>

// GCN: x[N,128] @ W1 -> 16, sym-norm scatter, relu; aggregate in 16-dim then
// @ W2 -> 64, relu, @ fcW -> 2, sum over nodes, log_softmax.
// Key algebraic move: A_norm @ (z1 @ W2) == (A_norm @ z1) @ W2, so both edge
// scatters run in the 16-dim space (4x fewer atomics/bytes for layer 2).

#define NF_IN 128
#define HID1 16

// ---- deg count: deg[c] += 1 per edge (self-loop +1 added in dinv pass) ----
__global__ void deg_count(const int* __restrict__ col, float* __restrict__ deg,
                          int E, int N) {
    int e = blockIdx.x * blockDim.x + threadIdx.x;
    if (e < E) {
        int c = col[e];
        if ((unsigned)c < (unsigned)N) atomicAdd(&deg[c], 1.0f);
    }
}

// ---- dinv[i] = rsqrt(deg[i] + 1) (in place) ----
__global__ void dinv_k(float* __restrict__ buf, int N) {
    int i = blockIdx.x * blockDim.x + threadIdx.x;
    if (i < N) buf[i] = rsqrtf(buf[i] + 1.0f);
}

// ---- h1 = x @ W1  [N,128]@[128,16] ; 16 nodes per 256-thread block ----
__global__ __launch_bounds__(256) void xw1_k(const float* __restrict__ x,
                                             const float* __restrict__ W1,
                                             float* __restrict__ h1, int N) {
    __shared__ float w[NF_IN * HID1];   // 2048 floats
    __shared__ float xs[16 * NF_IN];    // 2048 floats
    int t = threadIdx.x;
    for (int i = t; i < NF_IN * HID1; i += 256) w[i] = W1[i];
    int base = blockIdx.x * 16;
    int navail = min(16, N - base);
    const float* xp = x + (size_t)base * NF_IN;
    for (int i = t; i < navail * NF_IN; i += 256) xs[i] = xp[i];
    __syncthreads();
    int nl = t >> 4, j = t & 15;
    if (base + nl < N) {
        float acc = 0.0f;
        const float* xrow = &xs[nl * NF_IN];
        #pragma unroll 8
        for (int k = 0; k < NF_IN; ++k) acc += xrow[k] * w[k * HID1 + j];
        h1[(size_t)(base + nl) * HID1 + j] = acc;
    }
}

// ---- edge scatter in 16-dim: dst[c] += src[r] * dinv[r]*dinv[c] ----
// 4 threads per edge, each moves a float4 (4 atomicAdds).
__global__ __launch_bounds__(256) void scatter16(const int* __restrict__ row,
                                                 const int* __restrict__ col,
                                                 const float* __restrict__ dinv,
                                                 const float* __restrict__ src,
                                                 float* __restrict__ dst,
                                                 int E, int N) {
    int t = blockIdx.x * blockDim.x + threadIdx.x;
    int e = t >> 2, part = t & 3;
    if (e >= E) return;
    int r = row[e], c = col[e];
    if ((unsigned)r >= (unsigned)N || (unsigned)c >= (unsigned)N) return;
    float wgt = dinv[r] * dinv[c];
    float4 m = ((const float4*)(src + (size_t)r * HID1))[part];
    float* dp = dst + (size_t)c * HID1 + part * 4;
    atomicAdd(dp + 0, m.x * wgt);
    atomicAdd(dp + 1, m.y * wgt);
    atomicAdd(dp + 2, m.z * wgt);
    atomicAdd(dp + 3, m.w * wgt);
}

// ---- z1 = relu(agg1 + h1*dinv^2 (self-loop) + b1), in place in agg1 ----
__global__ void bias_relu_self(const float* __restrict__ h1,
                               const float* __restrict__ dinv,
                               const float* __restrict__ b1,
                               float* __restrict__ agg1, int N) {
    int t = blockIdx.x * blockDim.x + threadIdx.x;
    int n = t >> 4, j = t & 15;
    if (n >= N) return;
    float d = dinv[n];
    float v = agg1[(size_t)n * HID1 + j] + h1[(size_t)n * HID1 + j] * d * d + b1[j];
    agg1[(size_t)n * HID1 + j] = fmaxf(v, 0.0f);
}

// ---- epilogue: per node v=agg2+z1*dinv^2 (self-loop); y=relu(v@W2+b2);
//      p = y@fcW; block-reduce; atomicAdd into pooled[2] ----
__global__ __launch_bounds__(256) void final_k(const float* __restrict__ z1,
                                               const float* __restrict__ agg2,
                                               const float* __restrict__ dinv,
                                               const float* __restrict__ W2,
                                               const float* __restrict__ b2,
                                               const float* __restrict__ fcW,
                                               float* __restrict__ pooled, int N) {
    __shared__ float w2[HID1 * 64];  // 1024 floats
    __shared__ float fw[64 * 2];
    __shared__ float bb[64];
    int t = threadIdx.x;
    for (int i = t; i < HID1 * 64; i += 256) w2[i] = W2[i];
    if (t < 128) fw[t] = fcW[t];
    if (t < 64) bb[t] = b2[t];
    __syncthreads();
    int n = blockIdx.x * blockDim.x + t;
    float p0 = 0.0f, p1 = 0.0f;
    if (n < N) {
        float d = dinv[n];
        float d2 = d * d;
        float v[HID1];
        const float4* a4 = (const float4*)(agg2 + (size_t)n * HID1);
        const float4* z4 = (const float4*)(z1 + (size_t)n * HID1);
        #pragma unroll
        for (int q = 0; q < 4; ++q) {
            float4 a = a4[q], z = z4[q];
            v[q * 4 + 0] = a.x + z.x * d2;
            v[q * 4 + 1] = a.y + z.y * d2;
            v[q * 4 + 2] = a.z + z.z * d2;
            v[q * 4 + 3] = a.w + z.w * d2;
        }
        #pragma unroll 4
        for (int j = 0; j < 64; ++j) {
            float acc = bb[j];
            #pragma unroll
            for (int k = 0; k < HID1; ++k) acc += v[k] * w2[k * 64 + j];
            float y = fmaxf(acc, 0.0f);
            p0 += y * fw[j * 2 + 0];
            p1 += y * fw[j * 2 + 1];
        }
    }
    // wave (64-lane) reduction
    for (int off = 32; off > 0; off >>= 1) {
        p0 += __shfl_down(p0, off);
        p1 += __shfl_down(p1, off);
    }
    __shared__ float r0[4], r1[4];
    int wid = t >> 6, lane = t & 63;
    if (lane == 0) { r0[wid] = p0; r1[wid] = p1; }
    __syncthreads();
    if (t == 0) {
        atomicAdd(&pooled[0], r0[0] + r0[1] + r0[2] + r0[3]);
        atomicAdd(&pooled[1], r1[0] + r1[1] + r1[2] + r1[3]);
    }
}

// ---- log_softmax over pooled[2] + N*fcb ----
__global__ void logsm_k(const float* __restrict__ pooled,
                        const float* __restrict__ fcb,
                        float* __restrict__ out, float Nf) {
    if (threadIdx.x == 0 && blockIdx.x == 0) {
        float p0 = pooled[0] + Nf * fcb[0];
        float p1 = pooled[1] + Nf * fcb[1];
        float m = fmaxf(p0, p1);
        float lse = m + logf(expf(p0 - m) + expf(p1 - m));
        out[0] = p0 - lse;
        out[1] = p1 - lse;
    }
}

extern "C" void kernel_launch(void* const* d_in, const int* in_sizes, int n_in,
                              void* d_out, int out_size, void* d_ws, size_t ws_size,
                              hipStream_t stream) {
    const float* x   = (const float*)d_in[0];
    const int*   ei  = (const int*)d_in[1];   // edge_index [2,E] as int32
    const float* W1  = (const float*)d_in[2];
    const float* b1  = (const float*)d_in[3];
    const float* W2  = (const float*)d_in[4];
    const float* b2  = (const float*)d_in[5];
    const float* fcW = (const float*)d_in[6];
    const float* fcb = (const float*)d_in[7];
    float* out = (float*)d_out;

    int N = in_sizes[0] / NF_IN;
    int E = in_sizes[1] / 2;
    const int* row = ei;
    const int* col = ei + E;

    // workspace layout (floats): [dinv N | h1 16N | agg1 16N | agg2 16N | pooled 2]
    float* ws    = (float*)d_ws;
    float* dinv  = ws;
    float* h1    = ws + (size_t)N;
    float* agg1  = ws + (size_t)17 * N;
    float* agg2  = ws + (size_t)33 * N;
    float* pooled = ws + (size_t)49 * N;

    // zero: dinv region and agg1..pooled region (skip h1)
    hipMemsetAsync(dinv, 0, (size_t)N * sizeof(float), stream);
    hipMemsetAsync(agg1, 0, ((size_t)32 * N + 2) * sizeof(float), stream);

    int b256 = 256;
    // degree + dinv
    deg_count<<<(E + b256 - 1) / b256, b256, 0, stream>>>(col, dinv, E, N);
    dinv_k<<<(N + b256 - 1) / b256, b256, 0, stream>>>(dinv, N);
    // h1 = x @ W1
    xw1_k<<<(N + 15) / 16, b256, 0, stream>>>(x, W1, h1, N);
    // layer-1 scatter (edges only)
    long long total1 = (long long)E * 4;
    scatter16<<<(int)((total1 + b256 - 1) / b256), b256, 0, stream>>>(
        row, col, dinv, h1, agg1, E, N);
    // z1 = relu(agg1 + self-loop + b1), in place
    long long tn = (long long)N * HID1;
    bias_relu_self<<<(int)((tn + b256 - 1) / b256), b256, 0, stream>>>(
        h1, dinv, b1, agg1, N);
    // layer-2 scatter in 16-dim space
    scatter16<<<(int)((total1 + b256 - 1) / b256), b256, 0, stream>>>(
        row, col, dinv, agg1, agg2, E, N);
    // epilogue: W2, relu, fcW, pool
    final_k<<<(N + b256 - 1) / b256, b256, 0, stream>>>(
        agg1, agg2, dinv, W2, b2, fcW, pooled, N);
    // log_softmax (+ N * fcb)
    logsm_k<<<1, 64, 0, stream>>>(pooled, fcb, out, (float)N);
}

// Round 3
// 823.628 us; speedup vs baseline: 1.9351x; 1.9351x over previous
//
#include <hip/hip_runtime.h>
#include <math.h>

// GCN 2-layer + FC + global_add_pool + log_softmax.
// Round 3: scatter->gather via per-call CSR (counting sort by col).
// Atomics cut from 105.6M f32 RMWs to 6.4M int adds; aggregation is a
// deterministic-per-node gather with one coalesced write per output row.

#define NF_IN 128
#define HID1 16

// ---- int histogram of col ----
__global__ void hist_k(const int* __restrict__ col, int* __restrict__ deg,
                       int E, int N) {
    int e = blockIdx.x * blockDim.x + threadIdx.x;
    if (e < E) {
        int c = col[e];
        if ((unsigned)c < (unsigned)N) atomicAdd(&deg[c], 1);
    }
}

// ---- single-workgroup exclusive scan: starts[N+1], cursor[N] ----
__global__ __launch_bounds__(1024) void scan_k(const int* __restrict__ deg,
                                               int* __restrict__ starts,
                                               int* __restrict__ cursor, int N) {
    __shared__ int lds[1024];
    int t = threadIdx.x;
    int C = (N + 1023) >> 10;
    int lo = t * C, hi = min(lo + C, N);
    int local = 0;
    for (int i = lo; i < hi; ++i) local += deg[i];
    lds[t] = local;
    __syncthreads();
    for (int off = 1; off < 1024; off <<= 1) {
        int v = 0;
        if (t >= off) v = lds[t - off];
        __syncthreads();
        if (t >= off) lds[t] += v;
        __syncthreads();
    }
    int run = lds[t] - local;  // exclusive prefix
    for (int i = lo; i < hi; ++i) {
        starts[i] = run;
        cursor[i] = run;
        run += deg[i];
    }
    if (t == 1023) starts[N] = lds[1023];  // total = E
}

// ---- dinv[i] = rsqrt(deg[i] + 1)  (+1 = self-loop) ----
__global__ void dinv_k(const int* __restrict__ deg, float* __restrict__ dinv,
                       int N) {
    int i = blockIdx.x * blockDim.x + threadIdx.x;
    if (i < N) dinv[i] = rsqrtf((float)deg[i] + 1.0f);
}

// ---- h1 = x @ W1  [N,128]@[128,16]; 16 nodes per 256-thread block ----
__global__ __launch_bounds__(256) void xw1_k(const float* __restrict__ x,
                                             const float* __restrict__ W1,
                                             float* __restrict__ h1, int N) {
    __shared__ float w[NF_IN * HID1];
    __shared__ float xs[16 * NF_IN];
    int t = threadIdx.x;
    for (int i = t; i < NF_IN * HID1; i += 256) w[i] = W1[i];
    int base = blockIdx.x * 16;
    int navail = min(16, N - base);
    const float* xp = x + (size_t)base * NF_IN;
    for (int i = t; i < navail * NF_IN; i += 256) xs[i] = xp[i];
    __syncthreads();
    int nl = t >> 4, j = t & 15;
    if (base + nl < N) {
        float acc = 0.0f;
        const float* xrow = &xs[nl * NF_IN];
        #pragma unroll 8
        for (int k = 0; k < NF_IN; ++k) acc += xrow[k] * w[k * HID1 + j];
        h1[(size_t)(base + nl) * HID1 + j] = acc;
    }
}

// ---- build CSR entries: sorted[slot] = {row, dinv[r]*dinv[c]} ----
__global__ void build_k(const int* __restrict__ row, const int* __restrict__ col,
                        const float* __restrict__ dinv, int* __restrict__ cursor,
                        int2* __restrict__ sorted, int E, int N) {
    int e = blockIdx.x * blockDim.x + threadIdx.x;
    if (e >= E) return;
    int r = row[e], c = col[e];
    if ((unsigned)r >= (unsigned)N || (unsigned)c >= (unsigned)N) return;
    float w = dinv[r] * dinv[c];
    int slot = atomicAdd(&cursor[c], 1);
    sorted[slot] = make_int2(r, __float_as_int(w));
}

// ---- gather: dst[n] = sum_{edges->n} src[r]*w + src[n]*dinv[n]^2 (+b, relu) ----
// 4 threads per node, each owns one float4 slice of the 16-dim row.
__global__ __launch_bounds__(256) void gather16(const int2* __restrict__ sorted,
                                                const int* __restrict__ starts,
                                                const float* __restrict__ dinv,
                                                const float* __restrict__ src,
                                                const float* __restrict__ bias,
                                                float* __restrict__ dst,
                                                int N, int relu_mode) {
    int t = blockIdx.x * blockDim.x + threadIdx.x;
    int n = t >> 2, part = t & 3;
    if (n >= N) return;
    int s = starts[n], e = starts[n + 1];
    float4 acc = make_float4(0.f, 0.f, 0.f, 0.f);
    for (int i = s; i < e; ++i) {
        int2 en = sorted[i];
        float w = __int_as_float(en.y);
        float4 m = ((const float4*)(src + (size_t)en.x * HID1))[part];
        acc.x += m.x * w; acc.y += m.y * w;
        acc.z += m.z * w; acc.w += m.w * w;
    }
    float d = dinv[n], d2 = d * d;
    float4 sf = ((const float4*)(src + (size_t)n * HID1))[part];
    acc.x += sf.x * d2; acc.y += sf.y * d2;
    acc.z += sf.z * d2; acc.w += sf.w * d2;
    if (relu_mode) {
        float4 b = ((const float4*)bias)[part];
        acc.x = fmaxf(acc.x + b.x, 0.f);
        acc.y = fmaxf(acc.y + b.y, 0.f);
        acc.z = fmaxf(acc.z + b.z, 0.f);
        acc.w = fmaxf(acc.w + b.w, 0.f);
    }
    ((float4*)(dst + (size_t)n * HID1))[part] = acc;
}

// ---- epilogue: y = relu(v@W2 + b2); p = y@fcW; block-reduce; atomic pool ----
__global__ __launch_bounds__(256) void final_k(const float* __restrict__ v2,
                                               const float* __restrict__ W2,
                                               const float* __restrict__ b2,
                                               const float* __restrict__ fcW,
                                               float* __restrict__ pooled, int N) {
    __shared__ float w2[HID1 * 64];
    __shared__ float fw[64 * 2];
    __shared__ float bb[64];
    int t = threadIdx.x;
    for (int i = t; i < HID1 * 64; i += 256) w2[i] = W2[i];
    if (t < 128) fw[t] = fcW[t];
    if (t < 64) bb[t] = b2[t];
    __syncthreads();
    int n = blockIdx.x * blockDim.x + t;
    float p0 = 0.0f, p1 = 0.0f;
    if (n < N) {
        float v[HID1];
        const float4* a4 = (const float4*)(v2 + (size_t)n * HID1);
        #pragma unroll
        for (int q = 0; q < 4; ++q) {
            float4 a = a4[q];
            v[q * 4 + 0] = a.x; v[q * 4 + 1] = a.y;
            v[q * 4 + 2] = a.z; v[q * 4 + 3] = a.w;
        }
        #pragma unroll 4
        for (int j = 0; j < 64; ++j) {
            float acc = bb[j];
            #pragma unroll
            for (int k = 0; k < HID1; ++k) acc += v[k] * w2[k * 64 + j];
            float y = fmaxf(acc, 0.0f);
            p0 += y * fw[j * 2 + 0];
            p1 += y * fw[j * 2 + 1];
        }
    }
    for (int off = 32; off > 0; off >>= 1) {
        p0 += __shfl_down(p0, off);
        p1 += __shfl_down(p1, off);
    }
    __shared__ float r0[4], r1[4];
    int wid = t >> 6, lane = t & 63;
    if (lane == 0) { r0[wid] = p0; r1[wid] = p1; }
    __syncthreads();
    if (t == 0) {
        atomicAdd(&pooled[0], r0[0] + r0[1] + r0[2] + r0[3]);
        atomicAdd(&pooled[1], r1[0] + r1[1] + r1[2] + r1[3]);
    }
}

// ---- log_softmax over pooled[2] + N*fcb ----
__global__ void logsm_k(const float* __restrict__ pooled,
                        const float* __restrict__ fcb,
                        float* __restrict__ out, float Nf) {
    if (threadIdx.x == 0 && blockIdx.x == 0) {
        float p0 = pooled[0] + Nf * fcb[0];
        float p1 = pooled[1] + Nf * fcb[1];
        float m = fmaxf(p0, p1);
        float lse = m + logf(expf(p0 - m) + expf(p1 - m));
        out[0] = p0 - lse;
        out[1] = p1 - lse;
    }
}

extern "C" void kernel_launch(void* const* d_in, const int* in_sizes, int n_in,
                              void* d_out, int out_size, void* d_ws, size_t ws_size,
                              hipStream_t stream) {
    const float* x   = (const float*)d_in[0];
    const int*   ei  = (const int*)d_in[1];
    const float* W1  = (const float*)d_in[2];
    const float* b1  = (const float*)d_in[3];
    const float* W2  = (const float*)d_in[4];
    const float* b2  = (const float*)d_in[5];
    const float* fcW = (const float*)d_in[6];
    const float* fcb = (const float*)d_in[7];
    float* out = (float*)d_out;

    int N = in_sizes[0] / NF_IN;
    int E = in_sizes[1] / 2;
    const int* row = ei;
    const int* col = ei + E;

    // ws layout (4B units):
    // [deg_i N | starts N+1 | pad 1 | cursor N | dinv N | h1/v2 16N | z1 16N |
    //  pooled 2 | sorted 2E]
    int*   ws_i   = (int*)d_ws;
    float* ws_f   = (float*)d_ws;
    int*   deg_i  = ws_i;
    int*   starts = ws_i + (size_t)N;
    int*   cursor = ws_i + (size_t)2 * N + 2;
    float* dinv   = ws_f + (size_t)3 * N + 2;
    float* h1     = ws_f + (size_t)4 * N + 2;   // reused as v2 by gather2
    float* z1     = ws_f + (size_t)20 * N + 2;
    float* pooled = ws_f + (size_t)36 * N + 2;
    int2*  sorted = (int2*)(ws_f + (size_t)36 * N + 4);

    hipMemsetAsync(deg_i, 0, (size_t)N * sizeof(int), stream);
    hipMemsetAsync(pooled, 0, 2 * sizeof(float), stream);

    int b = 256;
    hist_k<<<(E + b - 1) / b, b, 0, stream>>>(col, deg_i, E, N);
    scan_k<<<1, 1024, 0, stream>>>(deg_i, starts, cursor, N);
    dinv_k<<<(N + b - 1) / b, b, 0, stream>>>(deg_i, dinv, N);
    xw1_k<<<(N + 15) / 16, b, 0, stream>>>(x, W1, h1, N);
    build_k<<<(E + b - 1) / b, b, 0, stream>>>(row, col, dinv, cursor, sorted, E, N);
    long long t4 = (long long)N * 4;
    // layer 1: gather h1 -> z1 (bias + relu fused)
    gather16<<<(int)((t4 + b - 1) / b), b, 0, stream>>>(
        sorted, starts, dinv, h1, b1, z1, N, 1);
    // layer 2 (pre-W2 space): gather z1 -> v2 (aliases h1)
    gather16<<<(int)((t4 + b - 1) / b), b, 0, stream>>>(
        sorted, starts, dinv, z1, b1, h1, N, 0);
    final_k<<<(N + b - 1) / b, b, 0, stream>>>(h1, W2, b2, fcW, pooled, N);
    logsm_k<<<1, 64, 0, stream>>>(pooled, fcb, out, (float)N);
}

// Round 4
// 585.092 us; speedup vs baseline: 2.7240x; 1.4077x over previous
//
#include <hip/hip_runtime.h>
#include <math.h>

// GCN 2-layer + FC + global_add_pool + log_softmax.
// Round 4: multi-block scan (391x256 -> 1x512 -> 391x256) replaces the
// single-workgroup scan that was 230us/28% of runtime at 0.15% occupancy.
// dinv fused into the scan-apply kernel.

#define NF_IN 128
#define HID1 16

// ---- int histogram of col ----
__global__ void hist_k(const int* __restrict__ col, int* __restrict__ deg,
                       int E, int N) {
    int e = blockIdx.x * blockDim.x + threadIdx.x;
    if (e < E) {
        int c = col[e];
        if ((unsigned)c < (unsigned)N) atomicAdd(&deg[c], 1);
    }
}

// ---- scan stage 1: per-block (256 elems) partial sums ----
__global__ __launch_bounds__(256) void partial_k(const int* __restrict__ deg,
                                                 int* __restrict__ partials, int N) {
    __shared__ int lds[256];
    int t = threadIdx.x;
    int i = blockIdx.x * 256 + t;
    lds[t] = (i < N) ? deg[i] : 0;
    __syncthreads();
    for (int off = 128; off > 0; off >>= 1) {
        if (t < off) lds[t] += lds[t + off];
        __syncthreads();
    }
    if (t == 0) partials[blockIdx.x] = lds[0];
}

// ---- scan stage 2: one block scans B<=512 partials -> exclusive offsets ----
__global__ __launch_bounds__(512) void scanp_k(const int* __restrict__ partials,
                                               int* __restrict__ offsets, int B) {
    __shared__ int lds[512];
    int t = threadIdx.x;
    int v = (t < B) ? partials[t] : 0;
    lds[t] = v;
    __syncthreads();
    for (int off = 1; off < 512; off <<= 1) {
        int u = (t >= off) ? lds[t - off] : 0;
        __syncthreads();
        lds[t] += u;
        __syncthreads();
    }
    if (t < B) offsets[t] = lds[t] - v;     // exclusive prefix
    if (t == B - 1) offsets[B] = lds[t];    // grand total = E
}

// ---- scan stage 3: per-block exclusive scan + offset; fused dinv ----
__global__ __launch_bounds__(256) void apply_k(const int* __restrict__ deg,
                                               const int* __restrict__ offsets,
                                               int* __restrict__ starts,
                                               int* __restrict__ cursor,
                                               float* __restrict__ dinv,
                                               int N, int B) {
    __shared__ int lds[256];
    int t = threadIdx.x;
    int i = blockIdx.x * 256 + t;
    int d = (i < N) ? deg[i] : 0;
    lds[t] = d;
    __syncthreads();
    for (int off = 1; off < 256; off <<= 1) {
        int u = (t >= off) ? lds[t - off] : 0;
        __syncthreads();
        lds[t] += u;
        __syncthreads();
    }
    int excl = lds[t] - d + offsets[blockIdx.x];
    if (i < N) {
        starts[i] = excl;
        cursor[i] = excl;
        dinv[i] = rsqrtf((float)d + 1.0f);
    }
    if (i == 0) starts[N] = offsets[B];
}

// ---- h1 = x @ W1  [N,128]@[128,16]; 16 nodes per 256-thread block ----
__global__ __launch_bounds__(256) void xw1_k(const float* __restrict__ x,
                                             const float* __restrict__ W1,
                                             float* __restrict__ h1, int N) {
    __shared__ float w[NF_IN * HID1];
    __shared__ float xs[16 * NF_IN];
    int t = threadIdx.x;
    for (int i = t; i < NF_IN * HID1; i += 256) w[i] = W1[i];
    int base = blockIdx.x * 16;
    int navail = min(16, N - base);
    const float* xp = x + (size_t)base * NF_IN;
    for (int i = t; i < navail * NF_IN; i += 256) xs[i] = xp[i];
    __syncthreads();
    int nl = t >> 4, j = t & 15;
    if (base + nl < N) {
        float acc = 0.0f;
        const float* xrow = &xs[nl * NF_IN];
        #pragma unroll 8
        for (int k = 0; k < NF_IN; ++k) acc += xrow[k] * w[k * HID1 + j];
        h1[(size_t)(base + nl) * HID1 + j] = acc;
    }
}

// ---- build CSR entries: sorted[slot] = {row, dinv[r]*dinv[c]} ----
__global__ void build_k(const int* __restrict__ row, const int* __restrict__ col,
                        const float* __restrict__ dinv, int* __restrict__ cursor,
                        int2* __restrict__ sorted, int E, int N) {
    int e = blockIdx.x * blockDim.x + threadIdx.x;
    if (e >= E) return;
    int r = row[e], c = col[e];
    if ((unsigned)r >= (unsigned)N || (unsigned)c >= (unsigned)N) return;
    float w = dinv[r] * dinv[c];
    int slot = atomicAdd(&cursor[c], 1);
    sorted[slot] = make_int2(r, __float_as_int(w));
}

// ---- gather: dst[n] = sum_{edges->n} src[r]*w + src[n]*dinv[n]^2 (+b, relu) ----
// 4 threads per node, each owns one float4 slice of the 16-dim row.
__global__ __launch_bounds__(256) void gather16(const int2* __restrict__ sorted,
                                                const int* __restrict__ starts,
                                                const float* __restrict__ dinv,
                                                const float* __restrict__ src,
                                                const float* __restrict__ bias,
                                                float* __restrict__ dst,
                                                int N, int relu_mode) {
    int t = blockIdx.x * blockDim.x + threadIdx.x;
    int n = t >> 2, part = t & 3;
    if (n >= N) return;
    int s = starts[n], e = starts[n + 1];
    float4 acc = make_float4(0.f, 0.f, 0.f, 0.f);
    for (int i = s; i < e; ++i) {
        int2 en = sorted[i];
        float w = __int_as_float(en.y);
        float4 m = ((const float4*)(src + (size_t)en.x * HID1))[part];
        acc.x += m.x * w; acc.y += m.y * w;
        acc.z += m.z * w; acc.w += m.w * w;
    }
    float d = dinv[n], d2 = d * d;
    float4 sf = ((const float4*)(src + (size_t)n * HID1))[part];
    acc.x += sf.x * d2; acc.y += sf.y * d2;
    acc.z += sf.z * d2; acc.w += sf.w * d2;
    if (relu_mode) {
        float4 b = ((const float4*)bias)[part];
        acc.x = fmaxf(acc.x + b.x, 0.f);
        acc.y = fmaxf(acc.y + b.y, 0.f);
        acc.z = fmaxf(acc.z + b.z, 0.f);
        acc.w = fmaxf(acc.w + b.w, 0.f);
    }
    ((float4*)(dst + (size_t)n * HID1))[part] = acc;
}

// ---- epilogue: y = relu(v@W2 + b2); p = y@fcW; block-reduce; atomic pool ----
__global__ __launch_bounds__(256) void final_k(const float* __restrict__ v2,
                                               const float* __restrict__ W2,
                                               const float* __restrict__ b2,
                                               const float* __restrict__ fcW,
                                               float* __restrict__ pooled, int N) {
    __shared__ float w2[HID1 * 64];
    __shared__ float fw[64 * 2];
    __shared__ float bb[64];
    int t = threadIdx.x;
    for (int i = t; i < HID1 * 64; i += 256) w2[i] = W2[i];
    if (t < 128) fw[t] = fcW[t];
    if (t < 64) bb[t] = b2[t];
    __syncthreads();
    int n = blockIdx.x * blockDim.x + t;
    float p0 = 0.0f, p1 = 0.0f;
    if (n < N) {
        float v[HID1];
        const float4* a4 = (const float4*)(v2 + (size_t)n * HID1);
        #pragma unroll
        for (int q = 0; q < 4; ++q) {
            float4 a = a4[q];
            v[q * 4 + 0] = a.x; v[q * 4 + 1] = a.y;
            v[q * 4 + 2] = a.z; v[q * 4 + 3] = a.w;
        }
        #pragma unroll 4
        for (int j = 0; j < 64; ++j) {
            float acc = bb[j];
            #pragma unroll
            for (int k = 0; k < HID1; ++k) acc += v[k] * w2[k * 64 + j];
            float y = fmaxf(acc, 0.0f);
            p0 += y * fw[j * 2 + 0];
            p1 += y * fw[j * 2 + 1];
        }
    }
    for (int off = 32; off > 0; off >>= 1) {
        p0 += __shfl_down(p0, off);
        p1 += __shfl_down(p1, off);
    }
    __shared__ float r0[4], r1[4];
    int wid = t >> 6, lane = t & 63;
    if (lane == 0) { r0[wid] = p0; r1[wid] = p1; }
    __syncthreads();
    if (t == 0) {
        atomicAdd(&pooled[0], r0[0] + r0[1] + r0[2] + r0[3]);
        atomicAdd(&pooled[1], r1[0] + r1[1] + r1[2] + r1[3]);
    }
}

// ---- log_softmax over pooled[2] + N*fcb ----
__global__ void logsm_k(const float* __restrict__ pooled,
                        const float* __restrict__ fcb,
                        float* __restrict__ out, float Nf) {
    if (threadIdx.x == 0 && blockIdx.x == 0) {
        float p0 = pooled[0] + Nf * fcb[0];
        float p1 = pooled[1] + Nf * fcb[1];
        float m = fmaxf(p0, p1);
        float lse = m + logf(expf(p0 - m) + expf(p1 - m));
        out[0] = p0 - lse;
        out[1] = p1 - lse;
    }
}

extern "C" void kernel_launch(void* const* d_in, const int* in_sizes, int n_in,
                              void* d_out, int out_size, void* d_ws, size_t ws_size,
                              hipStream_t stream) {
    const float* x   = (const float*)d_in[0];
    const int*   ei  = (const int*)d_in[1];
    const float* W1  = (const float*)d_in[2];
    const float* b1  = (const float*)d_in[3];
    const float* W2  = (const float*)d_in[4];
    const float* b2  = (const float*)d_in[5];
    const float* fcW = (const float*)d_in[6];
    const float* fcb = (const float*)d_in[7];
    float* out = (float*)d_out;

    int N = in_sizes[0] / NF_IN;
    int E = in_sizes[1] / 2;
    const int* row = ei;
    const int* col = ei + E;

    int B = (N + 255) / 256;   // scan blocks (391 for N=100k, must be <=512)

    // ws layout (4B units):
    // [deg_i N | starts N+1 | pad 1 | cursor N | dinv N | h1/v2 16N | z1 16N |
    //  pooled 2 | sorted 2E | partials B | offsets B+1]
    int*   ws_i   = (int*)d_ws;
    float* ws_f   = (float*)d_ws;
    int*   deg_i  = ws_i;
    int*   starts = ws_i + (size_t)N;
    int*   cursor = ws_i + (size_t)2 * N + 2;
    float* dinv   = ws_f + (size_t)3 * N + 2;
    float* h1     = ws_f + (size_t)4 * N + 2;   // reused as v2 by gather2
    float* z1     = ws_f + (size_t)20 * N + 2;
    float* pooled = ws_f + (size_t)36 * N + 2;
    int2*  sorted = (int2*)(ws_f + (size_t)36 * N + 4);
    int*   partials = (int*)(sorted + (size_t)E);
    int*   offsets  = partials + B;

    hipMemsetAsync(deg_i, 0, (size_t)N * sizeof(int), stream);
    hipMemsetAsync(pooled, 0, 2 * sizeof(float), stream);

    int b = 256;
    hist_k<<<(E + b - 1) / b, b, 0, stream>>>(col, deg_i, E, N);
    partial_k<<<B, 256, 0, stream>>>(deg_i, partials, N);
    scanp_k<<<1, 512, 0, stream>>>(partials, offsets, B);
    apply_k<<<B, 256, 0, stream>>>(deg_i, offsets, starts, cursor, dinv, N, B);
    xw1_k<<<(N + 15) / 16, b, 0, stream>>>(x, W1, h1, N);
    build_k<<<(E + b - 1) / b, b, 0, stream>>>(row, col, dinv, cursor, sorted, E, N);
    long long t4 = (long long)N * 4;
    // layer 1: gather h1 -> z1 (bias + relu fused)
    gather16<<<(int)((t4 + b - 1) / b), b, 0, stream>>>(
        sorted, starts, dinv, h1, b1, z1, N, 1);
    // layer 2 (pre-W2 space): gather z1 -> v2 (aliases h1)
    gather16<<<(int)((t4 + b - 1) / b), b, 0, stream>>>(
        sorted, starts, dinv, z1, b1, h1, N, 0);
    final_k<<<(N + b - 1) / b, b, 0, stream>>>(h1, W2, b2, fcW, pooled, N);
    logsm_k<<<1, 64, 0, stream>>>(pooled, fcb, out, (float)N);
}